// Round 4
// baseline (11345.049 us; speedup 1.0000x reference)
//
#include <hip/hip_runtime.h>

#define VOCABN 401
#define EN 256
#define HN 768
#define H3N 2304
#define ON 3
#define BN 64
#define TN 1024

// 16 replicas x 16 WGs; each WG: 48 j's, k split 8 ways, 4 batches
#define NREP 16
#define WGPR 16
#define BPR  4
#define JPW  48
#define NTH  384

typedef _Float16 f16x2 __attribute__((ext_vector_type(2)));
typedef _Float16 f16x8 __attribute__((ext_vector_type(8)));
union F16x8 { f16x8 v; f16x2 p[4]; };
union U32F16 { unsigned u; struct { unsigned short lo, hi; } s; };

__device__ __forceinline__ float fdot2(f16x2 a, f16x2 b, float c) {
#if __has_builtin(__builtin_amdgcn_fdot2)
    return __builtin_amdgcn_fdot2(a, b, c, false);
#else
    return c + (float)a[0] * (float)b[0] + (float)a[1] * (float)b[1];
#endif
}

// ---------------- K1: gtab[v][g] = dot(embed[v], W_ih[g]) + b_ih[g]
// w-stationary, vocab-chunked: grid (36, 4). thread (gl, ql): row g0+gl, k-quarter ql.
__global__ __launch_bounds__(256)
void k_build_gtab(const float* __restrict__ embed, const float* __restrict__ wih,
                  const float* __restrict__ bih, float* __restrict__ gtab) {
    const int g  = blockIdx.x * 64 + (threadIdx.x >> 2);
    const int ql = threadIdx.x & 3;
    const int v0 = blockIdx.y * 101;
    const int v1 = min(VOCABN, v0 + 101);
    float4 w[16];
    const float4* s4 = (const float4*)(wih + (size_t)g * EN + ql * 64);
#pragma unroll
    for (int i = 0; i < 16; ++i) w[i] = s4[i];
    const float bias = bih[g];
    for (int v = v0; v < v1; ++v) {
        const float4* e4 = (const float4*)(embed + (size_t)v * EN + ql * 64);
        float acc = 0.f;
#pragma unroll
        for (int i = 0; i < 16; ++i) {
            float4 e = e4[i];
            acc += w[i].x * e.x + w[i].y * e.y + w[i].z * e.z + w[i].w * e.w;
        }
        acc += __shfl_xor(acc, 1, 64);
        acc += __shfl_xor(acc, 2, 64);
        if (ql == 0) gtab[(size_t)v * H3N + g] = acc + bias;
    }
}

// ---------------- K2: persistent-weight recurrence, tag-in-data sync (no barrier).
// h word (4B): [31:16] = step tag (t+1), [15:0] = f16 h value. Agent-scope relaxed
// atomics through LLC. memset-0 == valid step-0 state (tag 0, h = +0).
__global__ __launch_bounds__(NTH, 1)
void k_rnn(const int* __restrict__ tokens, const float* __restrict__ whh,
           const float* __restrict__ gtab, const float* __restrict__ bhh,
           unsigned* __restrict__ hbuf, float* __restrict__ hout) {
    const int R   = blockIdx.x & (NREP - 1);   // bid%16: all 16 WGs of R on XCD R%8
    const int wg  = blockIdx.x >> 4;
    const int tid = threadIdx.x;
    const int jl  = tid >> 3;
    const int q   = tid & 7;
    const int j   = wg * JPW + jl;

    __shared__ int stok[BPR][TN];                     // 16384 B
    __shared__ __align__(16) _Float16 hlds[32 * 112]; // [b*8+q][96 data + 16 pad]

    for (int i = tid; i < BPR * TN; i += NTH)
        stok[i >> 10][i & 1023] = tokens[(size_t)(R * BPR + (i >> 10)) * TN + (i & 1023)];

    // ---- one-time: weight slice -> 36 statically-indexed f16x8
    F16x8 w[3][12];
#pragma unroll
    for (int g = 0; g < 3; ++g) {
        const float4* s4 = (const float4*)(whh + (size_t)(g * HN + j) * HN + q * 96);
#pragma unroll
        for (int c = 0; c < 12; ++c) {
            float4 a = s4[2 * c], b4 = s4[2 * c + 1];
            F16x8 t;
            t.v[0] = (_Float16)a.x;  t.v[1] = (_Float16)a.y;
            t.v[2] = (_Float16)a.z;  t.v[3] = (_Float16)a.w;
            t.v[4] = (_Float16)b4.x; t.v[5] = (_Float16)b4.y;
            t.v[6] = (_Float16)b4.z; t.v[7] = (_Float16)b4.w;
            w[g][c] = t;
        }
    }

    const float bhr = bhh[j], bhz = bhh[HN + j], bhn = bhh[2 * HN + j];
    unsigned* hb = hbuf + (size_t)R * (2 * BPR * HN);
    // loader constants: pair p = k2*384 + tid covers words (b=k2, j0=2*tid, 2*tid+1)
    const int lq  = tid / 48;        // q-slot of j0 = 2*tid  (j0/96)
    const int lo2 = 2 * tid - lq * 96;
    // per-batch LDS read bases for the dot loop
    const _Float16* hp0 = hlds + (0 * 8 + q) * 112;
    const _Float16* hp1 = hlds + (1 * 8 + q) * 112;
    const _Float16* hp2 = hlds + (2 * 8 + q) * 112;
    const _Float16* hp3 = hlds + (3 * 8 + q) * 112;

    float hprev = 0.f, xr = 0.f, xz = 0.f, xn = 0.f;
    __syncthreads();

    for (int t = 0; t < TN; ++t) {
        if (q < BPR) {                  // x-gate prefetch, in flight during the poll
            const float* g_ = gtab + (size_t)stok[q][t] * H3N;
            xr = g_[j]; xz = g_[HN + j]; xn = g_[2 * HN + j];
        }
        // ---- poll 4 x 8B tagged pairs (2 h-words each) until tag == t
        const unsigned long long* hin64 =
            (const unsigned long long*)(hb + (t & 1) * (BPR * HN));
        const unsigned want = (unsigned)t;
        unsigned long long v0, v1, v2, v3;
        v0 = __hip_atomic_load(&hin64[0 * NTH + tid], __ATOMIC_RELAXED, __HIP_MEMORY_SCOPE_AGENT);
        v1 = __hip_atomic_load(&hin64[1 * NTH + tid], __ATOMIC_RELAXED, __HIP_MEMORY_SCOPE_AGENT);
        v2 = __hip_atomic_load(&hin64[2 * NTH + tid], __ATOMIC_RELAXED, __HIP_MEMORY_SCOPE_AGENT);
        v3 = __hip_atomic_load(&hin64[3 * NTH + tid], __ATOMIC_RELAXED, __HIP_MEMORY_SCOPE_AGENT);
#define TAGOK(x) ((((unsigned)((x) >> 16)) & 0xffffu) == want && ((unsigned)((x) >> 48)) == want)
        while (!TAGOK(v0)) v0 = __hip_atomic_load(&hin64[0 * NTH + tid], __ATOMIC_RELAXED, __HIP_MEMORY_SCOPE_AGENT);
        while (!TAGOK(v1)) v1 = __hip_atomic_load(&hin64[1 * NTH + tid], __ATOMIC_RELAXED, __HIP_MEMORY_SCOPE_AGENT);
        while (!TAGOK(v2)) v2 = __hip_atomic_load(&hin64[2 * NTH + tid], __ATOMIC_RELAXED, __HIP_MEMORY_SCOPE_AGENT);
        while (!TAGOK(v3)) v3 = __hip_atomic_load(&hin64[3 * NTH + tid], __ATOMIC_RELAXED, __HIP_MEMORY_SCOPE_AGENT);
#undef TAGOK
        // ---- deposit f16 pairs into LDS: batch k2, j0 = 2*tid
        {
            union { unsigned long long u; U32F16 w2[2]; } c0, c1, c2, c3;
            c0.u = v0; c1.u = v1; c2.u = v2; c3.u = v3;
            f16x2 t2;
            unsigned short* dst;
            dst = (unsigned short*)(hlds + (0 * 8 + lq) * 112 + lo2);
            dst[0] = c0.w2[0].s.lo; dst[1] = c0.w2[1].s.lo;
            dst = (unsigned short*)(hlds + (1 * 8 + lq) * 112 + lo2);
            dst[0] = c1.w2[0].s.lo; dst[1] = c1.w2[1].s.lo;
            dst = (unsigned short*)(hlds + (2 * 8 + lq) * 112 + lo2);
            dst[0] = c2.w2[0].s.lo; dst[1] = c2.w2[1].s.lo;
            dst = (unsigned short*)(hlds + (3 * 8 + lq) * 112 + lo2);
            dst[0] = c3.w2[0].s.lo; dst[1] = c3.w2[1].s.lo;
            (void)t2;
        }
        __syncthreads();

        // ---- dot: c-outer (each weight reg read once), 12 live accumulators
        float ar[BPR], az[BPR], an[BPR];
#pragma unroll
        for (int b = 0; b < BPR; ++b) { ar[b] = 0.f; az[b] = 0.f; an[b] = 0.f; }
#pragma unroll
        for (int c = 0; c < 12; ++c) {
            const F16x8 w0 = w[0][c], w1 = w[1][c], w2 = w[2][c];
#pragma unroll
            for (int b = 0; b < BPR; ++b) {
                const _Float16* hp = (b == 0) ? hp0 : (b == 1) ? hp1 : (b == 2) ? hp2 : hp3;
                F16x8 hh; hh.v = ((const f16x8*)hp)[c];
#pragma unroll
                for (int p = 0; p < 4; ++p) {
                    ar[b] = fdot2(w0.p[p], hh.p[p], ar[b]);
                    az[b] = fdot2(w1.p[p], hh.p[p], az[b]);
                    an[b] = fdot2(w2.p[p], hh.p[p], an[b]);
                }
            }
        }
#pragma unroll
        for (int b = 0; b < BPR; ++b) {
            ar[b] += __shfl_xor(ar[b], 1, 64); ar[b] += __shfl_xor(ar[b], 2, 64); ar[b] += __shfl_xor(ar[b], 4, 64);
            az[b] += __shfl_xor(az[b], 1, 64); az[b] += __shfl_xor(az[b], 2, 64); az[b] += __shfl_xor(az[b], 4, 64);
            an[b] += __shfl_xor(an[b], 1, 64); an[b] += __shfl_xor(an[b], 2, 64); an[b] += __shfl_xor(an[b], 4, 64);
            if (q == b) {
                const float r  = 1.f / (1.f + __expf(-(xr + ar[b] + bhr)));
                const float z  = 1.f / (1.f + __expf(-(xz + az[b] + bhz)));
                const float nx = xn + r * (an[b] + bhn);
                const float n  = 1.f - 2.f / (__expf(2.f * nx) + 1.f);   // tanh
                hprev = (1.f - z) * n + z * hprev;
                if (t < TN - 1) {
                    U32F16 pk;
                    pk.s.lo = (unsigned short)__builtin_bit_cast(unsigned short, (_Float16)hprev);
                    pk.s.hi = (unsigned short)(t + 1);
                    __hip_atomic_store(&hb[((t + 1) & 1) * (BPR * HN) + b * HN + j], pk.u,
                                       __ATOMIC_RELAXED, __HIP_MEMORY_SCOPE_AGENT);
                } else {
                    hout[(size_t)(R * BPR + b) * HN + j] = hprev;
                }
            }
        }
        __syncthreads();   // hlds reads done before next iteration's fill
    }
}

// ---------------- K3: logits + log_softmax
__global__ void k_logits(const float* __restrict__ hfin, const float* __restrict__ wout,
                         const float* __restrict__ bout, float* __restrict__ lp) {
    const int b = blockIdx.x;
    const int o = threadIdx.x / 64;
    const int lane = threadIdx.x % 64;
    const float* hrow = hfin + (size_t)b * HN;
    const float* w = wout + (size_t)o * HN;
    float p = 0.f;
    for (int k = lane; k < HN; k += 64) p += hrow[k] * w[k];
    for (int off = 32; off > 0; off >>= 1) p += __shfl_down(p, off, 64);
    __shared__ float lg[ON];
    if (lane == 0) lg[o] = p + bout[o];
    __syncthreads();
    if (threadIdx.x == 0) {
        float m = fmaxf(lg[0], fmaxf(lg[1], lg[2]));
        float s = __expf(lg[0] - m) + __expf(lg[1] - m) + __expf(lg[2] - m);
        float ls = __logf(s);
        lp[b * ON + 0] = lg[0] - m - ls;
        lp[b * ON + 1] = lg[1] - m - ls;
        lp[b * ON + 2] = lg[2] - m - ls;
    }
}

extern "C" void kernel_launch(void* const* d_in, const int* in_sizes, int n_in,
                              void* d_out, int out_size, void* d_ws, size_t ws_size,
                              hipStream_t stream) {
    const int*   tokens = (const int*)d_in[0];
    // d_in[1] = hidden: reference zeroes it, ignored.
    const float* embed  = (const float*)d_in[2];
    const float* wih    = (const float*)d_in[3];
    const float* whh    = (const float*)d_in[4];
    const float* bih    = (const float*)d_in[5];
    const float* bhh    = (const float*)d_in[6];
    const float* wout   = (const float*)d_in[7];
    const float* bout   = (const float*)d_in[8];

    float* out = (float*)d_out;                  // [B*O logprobs][B*H h_final]
    char* ws = (char*)d_ws;
    const size_t GTAB_OFF = 0;                   // 401*2304*4 = 3,695,616
    const size_t HBUF_OFF = 3695616;             // 16*2*3072*4 = 393,216 (tagged u32)
    float*    gtab = (float*)(ws + GTAB_OFF);
    unsigned* hbuf = (unsigned*)(ws + HBUF_OFF);

    // tag protocol requires tag==0 state at t=0 on EVERY launch (graph-replayed)
    hipMemsetAsync(ws + HBUF_OFF, 0, 393216, stream);

    hipLaunchKernelGGL(k_build_gtab, dim3(H3N / 64, 4), dim3(256), 0, stream,
                       embed, wih, bih, gtab);
    hipLaunchKernelGGL(k_rnn, dim3(NREP * WGPR), dim3(NTH), 0, stream,
                       tokens, whh, gtab, bhh, hbuf, out + BN * ON);
    hipLaunchKernelGGL(k_logits, dim3(BN), dim3(192), 0, stream,
                       out + BN * ON, wout, bout, out);
}

// Round 5
// 11027.778 us; speedup vs baseline: 1.0288x; 1.0288x over previous
//
#include <hip/hip_runtime.h>

#define VOCABN 401
#define EN 256
#define HN 768
#define H3N 2304
#define ON 3
#define BN 64
#define TN 1024

// 16 replicas x 16 WGs; each WG: 48 j's, k split 8 ways, 4 batches
#define NREP 16
#define WGPR 16
#define BPR  4
#define JPW  48
#define NTH  384

typedef _Float16 f16x2 __attribute__((ext_vector_type(2)));
typedef _Float16 f16x8 __attribute__((ext_vector_type(8)));
typedef unsigned u32x4 __attribute__((ext_vector_type(4)));
union F16x8 { f16x8 v; f16x2 p[4]; };
union U32F16 { unsigned u; struct { unsigned short lo, hi; } s; };

__device__ __forceinline__ float fdot2(f16x2 a, f16x2 b, float c) {
#if __has_builtin(__builtin_amdgcn_fdot2)
    return __builtin_amdgcn_fdot2(a, b, c, false);
#else
    return c + (float)a[0] * (float)b[0] + (float)a[1] * (float)b[1];
#endif
}

// ---------------- K1: gtab[v][g] = dot(embed[v], W_ih[g]) + b_ih[g]
__global__ __launch_bounds__(256)
void k_build_gtab(const float* __restrict__ embed, const float* __restrict__ wih,
                  const float* __restrict__ bih, float* __restrict__ gtab) {
    const int g  = blockIdx.x * 64 + (threadIdx.x >> 2);
    const int ql = threadIdx.x & 3;
    const int v0 = blockIdx.y * 101;
    const int v1 = min(VOCABN, v0 + 101);
    float4 w[16];
    const float4* s4 = (const float4*)(wih + (size_t)g * EN + ql * 64);
#pragma unroll
    for (int i = 0; i < 16; ++i) w[i] = s4[i];
    const float bias = bih[g];
    for (int v = v0; v < v1; ++v) {
        const float4* e4 = (const float4*)(embed + (size_t)v * EN + ql * 64);
        float acc = 0.f;
#pragma unroll
        for (int i = 0; i < 16; ++i) {
            float4 e = e4[i];
            acc += w[i].x * e.x + w[i].y * e.y + w[i].z * e.z + w[i].w * e.w;
        }
        acc += __shfl_xor(acc, 1, 64);
        acc += __shfl_xor(acc, 2, 64);
        if (ql == 0) gtab[(size_t)v * H3N + g] = acc + bias;
    }
}

// ---------------- K2: persistent-weight recurrence, tag-in-data sync,
// coalesced sc0/sc1 (cache-bypass) wide loads/stores for the h exchange.
// h word (4B): [31:16] = step tag, [15:0] = f16 h value. memset-0 == valid t=0.
__global__ __launch_bounds__(NTH, 1)
void k_rnn(const int* __restrict__ tokens, const float* __restrict__ whh,
           const float* __restrict__ gtab, const float* __restrict__ bhh,
           unsigned* __restrict__ hbuf, float* __restrict__ hout) {
    const int R   = blockIdx.x & (NREP - 1);
    const int wg  = blockIdx.x >> 4;
    const int tid = threadIdx.x;
    const int jl  = tid >> 3;
    const int q   = tid & 7;
    const int j   = wg * JPW + jl;

    __shared__ int stok[BPR][TN];                          // 16384 B
    __shared__ __align__(16) _Float16 hlds[32 * 112];      // dot-input tile
    __shared__ __align__(16) unsigned hstage[BPR * JPW];   // produced tagged words

    for (int i = tid; i < BPR * TN; i += NTH)
        stok[i >> 10][i & 1023] = tokens[(size_t)(R * BPR + (i >> 10)) * TN + (i & 1023)];

    // ---- one-time: weight slice -> 36 statically-indexed f16x8
    F16x8 w[3][12];
#pragma unroll
    for (int g = 0; g < 3; ++g) {
        const float4* s4 = (const float4*)(whh + (size_t)(g * HN + j) * HN + q * 96);
#pragma unroll
        for (int c = 0; c < 12; ++c) {
            float4 a = s4[2 * c], b4 = s4[2 * c + 1];
            F16x8 t;
            t.v[0] = (_Float16)a.x;  t.v[1] = (_Float16)a.y;
            t.v[2] = (_Float16)a.z;  t.v[3] = (_Float16)a.w;
            t.v[4] = (_Float16)b4.x; t.v[5] = (_Float16)b4.y;
            t.v[6] = (_Float16)b4.z; t.v[7] = (_Float16)b4.w;
            w[g][c] = t;
        }
    }

    const float bhr = bhh[j], bhz = bhh[HN + j], bhn = bhh[2 * HN + j];
    unsigned* hb = hbuf + (size_t)R * (2 * BPR * HN);

    // consumer mapping: thread covers words [tid*8, tid*8+8) of the 3072-word set
    const int cb  = tid / 96;                 // batch of my 8 words
    const int cs  = (tid % 96) / 12;          // q-slot (j0/96)
    const int coff = ((tid % 96) % 12) * 8;   // j0%96
    _Float16* cdst = hlds + ((cb << 3) + cs) * 112 + coff;
    // producer mapping (tid<48): batch pb, 4 consecutive j starting at pj
    const int pb = tid / 12;
    const int pc = tid % 12;
    // per-batch LDS read bases for the dot loop
    const _Float16* hp0 = hlds + (0 * 8 + q) * 112;
    const _Float16* hp1 = hlds + (1 * 8 + q) * 112;
    const _Float16* hp2 = hlds + (2 * 8 + q) * 112;
    const _Float16* hp3 = hlds + (3 * 8 + q) * 112;

    float hprev = 0.f, xr = 0.f, xz = 0.f, xn = 0.f;
    __syncthreads();

    for (int t = 0; t < TN; ++t) {
        if (q < BPR) {                         // x-gate prefetch, in flight during poll
            const float* g_ = gtab + (size_t)stok[q][t] * H3N;
            xr = g_[j]; xz = g_[HN + j]; xn = g_[2 * HN + j];
        }
        // ---- poll 8 tagged words (2 x dwordx4, sc0 sc1 = L1+L2 bypass)
        const unsigned* pw = hb + (t & 1) * (BPR * HN) + tid * 8;
        const unsigned tgt = (unsigned)t << 16;
        u32x4 va, vb;
        for (;;) {
            asm volatile(
                "global_load_dwordx4 %0, %2, off sc0 sc1\n\t"
                "global_load_dwordx4 %1, %3, off sc0 sc1\n\t"
                "s_waitcnt vmcnt(0)"
                : "=&v"(va), "=&v"(vb)
                : "v"(pw), "v"(pw + 4)
                : "memory");
            unsigned m = (va[0] ^ tgt) | (va[1] ^ tgt) | (va[2] ^ tgt) | (va[3] ^ tgt)
                       | (vb[0] ^ tgt) | (vb[1] ^ tgt) | (vb[2] ^ tgt) | (vb[3] ^ tgt);
            if (!(m & 0xffff0000u)) break;
        }
        // ---- deposit 8 f16 into the dot tile (one ds_write_b128)
        {
            union { f16x8 v; unsigned short u[8]; } hv;
            hv.u[0] = (unsigned short)va[0]; hv.u[1] = (unsigned short)va[1];
            hv.u[2] = (unsigned short)va[2]; hv.u[3] = (unsigned short)va[3];
            hv.u[4] = (unsigned short)vb[0]; hv.u[5] = (unsigned short)vb[1];
            hv.u[6] = (unsigned short)vb[2]; hv.u[7] = (unsigned short)vb[3];
            *(f16x8*)cdst = hv.v;
        }
        __syncthreads();

        // ---- dot: c-outer (each weight reg read once), 12 live accumulators
        float ar[BPR], az[BPR], an[BPR];
#pragma unroll
        for (int b = 0; b < BPR; ++b) { ar[b] = 0.f; az[b] = 0.f; an[b] = 0.f; }
#pragma unroll
        for (int c = 0; c < 12; ++c) {
            const F16x8 w0 = w[0][c], w1 = w[1][c], w2 = w[2][c];
#pragma unroll
            for (int b = 0; b < BPR; ++b) {
                const _Float16* hp = (b == 0) ? hp0 : (b == 1) ? hp1 : (b == 2) ? hp2 : hp3;
                F16x8 hh; hh.v = ((const f16x8*)hp)[c];
#pragma unroll
                for (int p = 0; p < 4; ++p) {
                    ar[b] = fdot2(w0.p[p], hh.p[p], ar[b]);
                    az[b] = fdot2(w1.p[p], hh.p[p], az[b]);
                    an[b] = fdot2(w2.p[p], hh.p[p], an[b]);
                }
            }
        }
#pragma unroll
        for (int b = 0; b < BPR; ++b) {
            ar[b] += __shfl_xor(ar[b], 1, 64); ar[b] += __shfl_xor(ar[b], 2, 64); ar[b] += __shfl_xor(ar[b], 4, 64);
            az[b] += __shfl_xor(az[b], 1, 64); az[b] += __shfl_xor(az[b], 2, 64); az[b] += __shfl_xor(az[b], 4, 64);
            an[b] += __shfl_xor(an[b], 1, 64); an[b] += __shfl_xor(an[b], 2, 64); an[b] += __shfl_xor(an[b], 4, 64);
            if (q == b) {
                const float r  = 1.f / (1.f + __expf(-(xr + ar[b] + bhr)));
                const float z  = 1.f / (1.f + __expf(-(xz + az[b] + bhz)));
                const float nx = xn + r * (an[b] + bhn);
                const float n  = 1.f - 2.f / (__expf(2.f * nx) + 1.f);   // tanh
                hprev = (1.f - z) * n + z * hprev;
                if (t < TN - 1) {
                    U32F16 pk;
                    pk.s.lo = (unsigned short)__builtin_bit_cast(unsigned short, (_Float16)hprev);
                    pk.s.hi = (unsigned short)(t + 1);
                    hstage[b * JPW + jl] = pk.u;
                } else {
                    hout[(size_t)(R * BPR + b) * HN + j] = hprev;
                }
            }
        }
        if (t < TN - 1) {
            __syncthreads();                   // hstage complete; hlds reads done
            if (tid < BPR * 12) {              // 48 threads: one dwordx4 each
                u32x4 val = *(const u32x4*)&hstage[pb * JPW + pc * 4];
                unsigned* dst = hb + ((t + 1) & 1) * (BPR * HN) + pb * HN + wg * JPW + pc * 4;
                asm volatile("global_store_dwordx4 %0, %1, off sc0 sc1"
                             :: "v"(dst), "v"(val) : "memory");
            }
        }
    }
}

// ---------------- K3: logits + log_softmax
__global__ void k_logits(const float* __restrict__ hfin, const float* __restrict__ wout,
                         const float* __restrict__ bout, float* __restrict__ lp) {
    const int b = blockIdx.x;
    const int o = threadIdx.x / 64;
    const int lane = threadIdx.x % 64;
    const float* hrow = hfin + (size_t)b * HN;
    const float* w = wout + (size_t)o * HN;
    float p = 0.f;
    for (int k = lane; k < HN; k += 64) p += hrow[k] * w[k];
    for (int off = 32; off > 0; off >>= 1) p += __shfl_down(p, off, 64);
    __shared__ float lg[ON];
    if (lane == 0) lg[o] = p + bout[o];
    __syncthreads();
    if (threadIdx.x == 0) {
        float m = fmaxf(lg[0], fmaxf(lg[1], lg[2]));
        float s = __expf(lg[0] - m) + __expf(lg[1] - m) + __expf(lg[2] - m);
        float ls = __logf(s);
        lp[b * ON + 0] = lg[0] - m - ls;
        lp[b * ON + 1] = lg[1] - m - ls;
        lp[b * ON + 2] = lg[2] - m - ls;
    }
}

extern "C" void kernel_launch(void* const* d_in, const int* in_sizes, int n_in,
                              void* d_out, int out_size, void* d_ws, size_t ws_size,
                              hipStream_t stream) {
    const int*   tokens = (const int*)d_in[0];
    // d_in[1] = hidden: reference zeroes it, ignored.
    const float* embed  = (const float*)d_in[2];
    const float* wih    = (const float*)d_in[3];
    const float* whh    = (const float*)d_in[4];
    const float* bih    = (const float*)d_in[5];
    const float* bhh    = (const float*)d_in[6];
    const float* wout   = (const float*)d_in[7];
    const float* bout   = (const float*)d_in[8];

    float* out = (float*)d_out;                  // [B*O logprobs][B*H h_final]
    char* ws = (char*)d_ws;
    const size_t GTAB_OFF = 0;                   // 401*2304*4 = 3,695,616
    const size_t HBUF_OFF = 3695616;             // 16*2*3072*4 = 393,216 (tagged u32)
    float*    gtab = (float*)(ws + GTAB_OFF);
    unsigned* hbuf = (unsigned*)(ws + HBUF_OFF);

    // tag protocol requires tag==0 state at t=0 on EVERY launch (graph-replayed)
    hipMemsetAsync(ws + HBUF_OFF, 0, 393216, stream);

    hipLaunchKernelGGL(k_build_gtab, dim3(H3N / 64, 4), dim3(256), 0, stream,
                       embed, wih, bih, gtab);
    hipLaunchKernelGGL(k_rnn, dim3(NREP * WGPR), dim3(NTH), 0, stream,
                       tokens, whh, gtab, bhh, hbuf, out + BN * ON);
    hipLaunchKernelGGL(k_logits, dim3(BN), dim3(192), 0, stream,
                       out + BN * ON, wout, bout, out);
}